// Round 7
// baseline (219.255 us; speedup 1.0000x reference)
//
#include <hip/hip_runtime.h>
#include <hip/hip_cooperative_groups.h>

namespace cg = cooperative_groups;

// GAT: N=4096, F_IN=128, F_HID=64, H=4, F_OUT=64, alpha=0.2
#define GN 4096
#define F_IN 128
#define F_HID 64
#define NHEADS 4
#define F_OUT 64
#define ALPHA 0.2f
#define MAX_DEG 256
#define NBLK 512           // 8 rows/nodes per block

// workspace layout (bytes)
#define OFF_WH     0           // GN*256*4 = 4 MB
#define OFF_SRC1   4194304
#define OFF_DST1   4259840
#define OFF_WH2    4325376     // GN*64*4 = 1 MB
#define OFF_SRC2   5373952
#define OFF_DST2   5390336
#define OFF_CNT    5406720
#define OFF_IDX    5423104     // GN*MAX_DEG*4 = 4 MB

struct SMemA {
    int   sidx[4][264];
    int   scnt[4];
    float xs[8][128];
    float hs[8][128];
};
struct SMemB {
    float ps[4][4][260];       // [wave][head][neighbor] normalized weights
    float hcat[8][256];        // per-node concat row, consumed in-block
};
union SMem { SMemA a; SMemB b; };

// ============ Phase A: compact 8 adj rows + fused lin/Wh/srcdst1 ============
__device__ __forceinline__ void phaseA(
        const float* __restrict__ adj, const float* __restrict__ x,
        const float* __restrict__ linW, const float* __restrict__ linb,
        const float* __restrict__ Wheads, const float* __restrict__ aheads,
        float* __restrict__ Wh, float* __restrict__ src1, float* __restrict__ dst1,
        int* __restrict__ cnt, int* __restrict__ idx, int i0, SMemA& a) {
    const int tid = threadIdx.x;
    const int wave = tid >> 6, lane = tid & 63;
    for (int r = 0; r < 8; ++r) {
        const int row = i0 + r;
        const float4* a4 = (const float4*)(adj + (size_t)row * GN) + wave * 256;
        int count = 0;
        #pragma unroll
        for (int it = 0; it < 4; ++it) {
            float4 v = a4[it * 64 + lane];
            bool b0 = v.x > 0.0f, b1 = v.y > 0.0f, b2 = v.z > 0.0f, b3 = v.w > 0.0f;
            unsigned long long m0 = __ballot(b0), m1 = __ballot(b1);
            unsigned long long m2 = __ballot(b2), m3 = __ballot(b3);
            int p0 = __builtin_amdgcn_mbcnt_hi((unsigned)(m0 >> 32), __builtin_amdgcn_mbcnt_lo((unsigned)m0, 0u));
            int p1 = __builtin_amdgcn_mbcnt_hi((unsigned)(m1 >> 32), __builtin_amdgcn_mbcnt_lo((unsigned)m1, 0u));
            int p2 = __builtin_amdgcn_mbcnt_hi((unsigned)(m2 >> 32), __builtin_amdgcn_mbcnt_lo((unsigned)m2, 0u));
            int p3 = __builtin_amdgcn_mbcnt_hi((unsigned)(m3 >> 32), __builtin_amdgcn_mbcnt_lo((unsigned)m3, 0u));
            int c0 = __popcll(m0), c1 = __popcll(m1), c2 = __popcll(m2), c3 = __popcll(m3);
            int col = wave * 1024 + it * 256 + lane * 4;
            int pos = count + p0;
            if (b0 && pos < 264) a.sidx[wave][pos] = col;
            pos = count + c0 + p1;
            if (b1 && pos < 264) a.sidx[wave][pos] = col + 1;
            pos = count + c0 + c1 + p2;
            if (b2 && pos < 264) a.sidx[wave][pos] = col + 2;
            pos = count + c0 + c1 + c2 + p3;
            if (b3 && pos < 264) a.sidx[wave][pos] = col + 3;
            count += c0 + c1 + c2 + c3;
        }
        if (lane == 0) a.scnt[wave] = count;
        __syncthreads();
        int base = 0;
        #pragma unroll
        for (int w = 0; w < 3; ++w) base += (w < wave) ? a.scnt[w] : 0;
        const int total = a.scnt[0] + a.scnt[1] + a.scnt[2] + a.scnt[3];
        const int cc = (total > MAX_DEG) ? MAX_DEG : total;
        int* outp = idx + (size_t)row * MAX_DEG;
        for (int t = lane; t < count; t += 64) {
            int pos = base + t;
            if (pos < MAX_DEG) outp[pos] = a.sidx[wave][t];
        }
        if (tid < 4) {
            int pad = ((cc + 3) & ~3) - cc;
            if (tid < pad) outp[cc + tid] = 0;     // padded entries -> weight exactly 0
            if (tid == 0) cnt[row] = cc;
        }
        __syncthreads();
    }

    // fused1 for 8 nodes
    #pragma unroll
    for (int t = 0; t < 4; ++t) {
        int e = t * 256 + tid;
        a.xs[e >> 7][e & 127] = x[(size_t)i0 * 128 + e];
    }
    __syncthreads();
    {
        const int k = tid & 127;
        const int n0 = tid >> 7;               // nodes {n0, n0+2, n0+4, n0+6}
        float bk = linb[k];
        float a0 = bk, a1 = bk, a2 = bk, a3 = bk;
        for (int j = 0; j < 128; ++j) {
            float w = linW[j * 128 + k];
            a0 += a.xs[n0][j] * w;
            a1 += a.xs[n0 + 2][j] * w;
            a2 += a.xs[n0 + 4][j] * w;
            a3 += a.xs[n0 + 6][j] * w;
        }
        a.hs[n0][k] = a0; a.hs[n0 + 2][k] = a1; a.hs[n0 + 4][k] = a2; a.hs[n0 + 6][k] = a3;
    }
    __syncthreads();
    {
        const int hd = tid >> 6, f = tid & 63;
        float acc[8] = {0, 0, 0, 0, 0, 0, 0, 0};
        const float* Wp = Wheads + (size_t)hd * F_IN * F_HID + f;
        for (int j = 0; j < 128; ++j) {
            float w = Wp[j * 64];
            #pragma unroll
            for (int n = 0; n < 8; ++n) acc[n] += a.hs[n][j] * w;
        }
        const float as = aheads[hd * 128 + f];
        const float ad = aheads[hd * 128 + 64 + f];
        #pragma unroll
        for (int n = 0; n < 8; ++n) {
            Wh[(size_t)(i0 + n) * 256 + hd * 64 + f] = acc[n];
            float sv = acc[n] * as, dv = acc[n] * ad;
            #pragma unroll
            for (int o = 32; o > 0; o >>= 1) {
                sv += __shfl_xor(sv, o, 64);
                dv += __shfl_xor(dv, o, 64);
            }
            if (f == 0) { src1[hd * GN + i0 + n] = sv; dst1[hd * GN + i0 + n] = dv; }
        }
    }
}

// ===== Phase B+C: layer-1 attention (hcat in LDS) + Wh2/src2/dst2, 8 rows =====
__device__ __forceinline__ void phaseBC(
        const float* __restrict__ Wh, const float* __restrict__ src1,
        const float* __restrict__ dst1, const float* __restrict__ Wend,
        const float* __restrict__ aend, float* __restrict__ Wh2,
        float* __restrict__ src2, float* __restrict__ dst2,
        const int* __restrict__ cnt, const int* __restrict__ idx, int i0, SMemB& b) {
    const int tid = threadIdx.x;
    const int wave = tid >> 6, lane = tid & 63;

    #pragma unroll
    for (int rr = 0; rr < 2; ++rr) {
        const int rloc = wave + rr * 4;
        const int row  = i0 + rloc;
        const int deg  = cnt[row];
        const int* nb  = idx + (size_t)row * MAX_DEG;
        const int nchunk = (deg + 63) >> 6;
        #pragma unroll
        for (int hd = 0; hd < 4; ++hd) {
            const float s_i = src1[hd * GN + row];
            float e[4];
            float m = -1e30f;
            for (int c = 0; c < nchunk; ++c) {
                int t = c * 64 + lane;
                float ev = -1e30f;
                if (t < deg) {
                    int j = nb[t];
                    ev = s_i + dst1[hd * GN + j];
                    ev = (ev > 0.0f) ? ev : ALPHA * ev;
                }
                e[c] = ev; m = fmaxf(m, ev);
            }
            #pragma unroll
            for (int o = 32; o > 0; o >>= 1) m = fmaxf(m, __shfl_xor(m, o, 64));
            float l = 0.0f;
            for (int c = 0; c < nchunk; ++c) { e[c] = expf(e[c] - m); l += e[c]; }
            #pragma unroll
            for (int o = 32; o > 0; o >>= 1) l += __shfl_xor(l, o, 64);
            float inv = 1.0f / l;
            for (int c = 0; c < nchunk; ++c) b.ps[wave][hd][c * 64 + lane] = e[c] * inv;
        }
        const int hl = lane >> 4;
        const float4* Wh4 = (const float4*)Wh;
        float4 acc = make_float4(0.f, 0.f, 0.f, 0.f);
        const int deg4 = (deg + 3) & ~3;
        for (int t = 0; t < deg4; t += 4) {
            int4 jj = *(const int4*)(nb + t);
            float p0 = b.ps[wave][hl][t],     p1 = b.ps[wave][hl][t + 1];
            float p2 = b.ps[wave][hl][t + 2], p3 = b.ps[wave][hl][t + 3];
            float4 v0 = Wh4[(size_t)jj.x * 64 + lane];
            float4 v1 = Wh4[(size_t)jj.y * 64 + lane];
            float4 v2 = Wh4[(size_t)jj.z * 64 + lane];
            float4 v3 = Wh4[(size_t)jj.w * 64 + lane];
            acc.x += p0 * v0.x + p1 * v1.x + p2 * v2.x + p3 * v3.x;
            acc.y += p0 * v0.y + p1 * v1.y + p2 * v2.y + p3 * v3.y;
            acc.z += p0 * v0.z + p1 * v1.z + p2 * v2.z + p3 * v3.z;
            acc.w += p0 * v0.w + p1 * v1.w + p2 * v2.w + p3 * v3.w;
        }
        acc.x = (acc.x > 0.0f) ? acc.x : expm1f(acc.x);
        acc.y = (acc.y > 0.0f) ? acc.y : expm1f(acc.y);
        acc.z = (acc.z > 0.0f) ? acc.z : expm1f(acc.z);
        acc.w = (acc.w > 0.0f) ? acc.w : expm1f(acc.w);
        ((float4*)b.hcat[rloc])[lane] = acc;       // stays in LDS
    }

    // Phase C: wave handles nodes {wave, wave+4} — exactly the hcat rows it wrote
    #pragma unroll
    for (int rr = 0; rr < 2; ++rr) {
        const int rloc = wave + rr * 4;
        const int node = i0 + rloc;
        const int f = lane;
        float a0 = 0.0f;
        const float* Wp = Wend + f;
        for (int j = 0; j < 256; ++j) a0 += b.hcat[rloc][j] * Wp[j * 64];
        Wh2[(size_t)node * 64 + f] = a0;
        float s0 = a0 * aend[f], d0 = a0 * aend[64 + f];
        #pragma unroll
        for (int o = 32; o > 0; o >>= 1) {
            s0 += __shfl_xor(s0, o, 64); d0 += __shfl_xor(d0, o, 64);
        }
        if (f == 0) { src2[node] = s0; dst2[node] = d0; }
    }
}

// ===== Phase D: layer-2 attention + elu + final row softmax, 8 rows =====
__device__ __forceinline__ void phaseD(
        const float* __restrict__ Wh2, const float* __restrict__ src2,
        const float* __restrict__ dst2, const int* __restrict__ cnt,
        const int* __restrict__ idx, float* __restrict__ out, int i0) {
    const int tid = threadIdx.x;
    const int wave = tid >> 6, lane = tid & 63;
    #pragma unroll
    for (int rr = 0; rr < 2; ++rr) {
        const int row = i0 + wave + rr * 4;
        const int deg = cnt[row];
        const int* nb = idx + (size_t)row * MAX_DEG;
        const float s_i = src2[row];
        float e[4];
        #pragma unroll
        for (int c = 0; c < 4; ++c) {
            int t = c * 64 + lane;
            float ev = -1e30f;
            if (t < deg) {
                int j = nb[t];
                ev = s_i + dst2[j];
                ev = (ev > 0.0f) ? ev : ALPHA * ev;
            }
            e[c] = ev;
        }
        float m = fmaxf(fmaxf(e[0], e[1]), fmaxf(e[2], e[3]));
        #pragma unroll
        for (int o = 32; o > 0; o >>= 1) m = fmaxf(m, __shfl_xor(m, o, 64));
        float l = 0.0f;
        #pragma unroll
        for (int c = 0; c < 4; ++c) { e[c] = expf(e[c] - m); l += e[c]; }
        #pragma unroll
        for (int o = 32; o > 0; o >>= 1) l += __shfl_xor(l, o, 64);

        float accA = 0.0f, accB = 0.0f;
        const float* W2 = Wh2 + lane;
        #pragma unroll
        for (int c = 0; c < 4; ++c) {
            int base = c * 64;
            if (base >= deg) break;
            int nmax = deg - base; if (nmax > 64) nmax = 64;
            int n4 = (nmax + 3) & ~3;
            for (int t = 0; t < n4; t += 4) {
                float p0 = __shfl(e[c], t, 64);
                float p1 = __shfl(e[c], t + 1, 64);
                float p2 = __shfl(e[c], t + 2, 64);
                float p3 = __shfl(e[c], t + 3, 64);
                int4 jj = *(const int4*)(nb + base + t);
                accA += p0 * W2[(size_t)jj.x * 64];
                accB += p1 * W2[(size_t)jj.y * 64];
                accA += p2 * W2[(size_t)jj.z * 64];
                accB += p3 * W2[(size_t)jj.w * 64];
            }
        }
        float v = (accA + accB) / l;
        v = (v > 0.0f) ? v : expm1f(v);    // elu

        float mm = v;
        #pragma unroll
        for (int o = 32; o > 0; o >>= 1) mm = fmaxf(mm, __shfl_xor(mm, o, 64));
        float ee = expf(v - mm);
        float ss = ee;
        #pragma unroll
        for (int o = 32; o > 0; o >>= 1) ss += __shfl_xor(ss, o, 64);
        out[(size_t)row * F_OUT + lane] = ee / ss;
    }
}

// ================== cooperative megakernel ==================
__global__ __launch_bounds__(256) void gat_mega(
        const float* __restrict__ adj, const float* __restrict__ x,
        const float* __restrict__ linW, const float* __restrict__ linb,
        const float* __restrict__ Wheads, const float* __restrict__ aheads,
        const float* __restrict__ Wend, const float* __restrict__ aend,
        float* __restrict__ Wh, float* __restrict__ src1, float* __restrict__ dst1,
        float* __restrict__ Wh2, float* __restrict__ src2, float* __restrict__ dst2,
        int* __restrict__ cnt, int* __restrict__ idx, float* __restrict__ out) {
    __shared__ SMem sm;
    cg::grid_group grid = cg::this_grid();
    const int i0 = blockIdx.x * 8;
    phaseA(adj, x, linW, linb, Wheads, aheads, Wh, src1, dst1, cnt, idx, i0, sm.a);
    grid.sync();
    phaseBC(Wh, src1, dst1, Wend, aend, Wh2, src2, dst2, cnt, idx, i0, sm.b);
    grid.sync();
    phaseD(Wh2, src2, dst2, cnt, idx, out, i0);
}

// ================== fallback: same phases, 3 dispatches ==================
__global__ __launch_bounds__(256) void kA(
        const float* __restrict__ adj, const float* __restrict__ x,
        const float* __restrict__ linW, const float* __restrict__ linb,
        const float* __restrict__ Wheads, const float* __restrict__ aheads,
        float* __restrict__ Wh, float* __restrict__ src1, float* __restrict__ dst1,
        int* __restrict__ cnt, int* __restrict__ idx) {
    __shared__ SMemA a;
    phaseA(adj, x, linW, linb, Wheads, aheads, Wh, src1, dst1, cnt, idx, blockIdx.x * 8, a);
}
__global__ __launch_bounds__(256) void kBC(
        const float* __restrict__ Wh, const float* __restrict__ src1,
        const float* __restrict__ dst1, const float* __restrict__ Wend,
        const float* __restrict__ aend, float* __restrict__ Wh2,
        float* __restrict__ src2, float* __restrict__ dst2,
        const int* __restrict__ cnt, const int* __restrict__ idx) {
    __shared__ SMemB b;
    phaseBC(Wh, src1, dst1, Wend, aend, Wh2, src2, dst2, cnt, idx, blockIdx.x * 8, b);
}
__global__ __launch_bounds__(256) void kD(
        const float* __restrict__ Wh2, const float* __restrict__ src2,
        const float* __restrict__ dst2, const int* __restrict__ cnt,
        const int* __restrict__ idx, float* __restrict__ out) {
    phaseD(Wh2, src2, dst2, cnt, idx, out, blockIdx.x * 8);
}

extern "C" void kernel_launch(void* const* d_in, const int* in_sizes, int n_in,
                              void* d_out, int out_size, void* d_ws, size_t ws_size,
                              hipStream_t stream) {
    const float* x      = (const float*)d_in[0];
    const float* adj    = (const float*)d_in[1];
    const float* lin_W  = (const float*)d_in[2];
    const float* lin_b  = (const float*)d_in[3];
    const float* Wheads = (const float*)d_in[4];
    const float* aheads = (const float*)d_in[5];
    const float* Wend   = (const float*)d_in[6];
    const float* aend   = (const float*)d_in[7];
    float* out = (float*)d_out;

    char* ws = (char*)d_ws;
    float* Wh   = (float*)(ws + OFF_WH);
    float* src1 = (float*)(ws + OFF_SRC1);
    float* dst1 = (float*)(ws + OFF_DST1);
    float* Wh2  = (float*)(ws + OFF_WH2);
    float* src2 = (float*)(ws + OFF_SRC2);
    float* dst2 = (float*)(ws + OFF_DST2);
    int*   cnt  = (int*)(ws + OFF_CNT);
    int*   nidx = (int*)(ws + OFF_IDX);

    void* args[] = {
        (void*)&adj, (void*)&x, (void*)&lin_W, (void*)&lin_b,
        (void*)&Wheads, (void*)&aheads, (void*)&Wend, (void*)&aend,
        (void*)&Wh, (void*)&src1, (void*)&dst1,
        (void*)&Wh2, (void*)&src2, (void*)&dst2,
        (void*)&cnt, (void*)&nidx, (void*)&out
    };
    hipError_t err = hipLaunchCooperativeKernel((const void*)gat_mega, dim3(NBLK),
                                                dim3(256), args, 0, stream);
    if (err != hipSuccess) {
        // deterministic fallback: same phases as 3 regular dispatches
        kA<<<NBLK, 256, 0, stream>>>(adj, x, lin_W, lin_b, Wheads, aheads,
                                     Wh, src1, dst1, cnt, nidx);
        kBC<<<NBLK, 256, 0, stream>>>(Wh, src1, dst1, Wend, aend,
                                      Wh2, src2, dst2, cnt, nidx);
        kD<<<NBLK, 256, 0, stream>>>(Wh2, src2, dst2, cnt, nidx, out);
    }
}

// Round 8
// 58.980 us; speedup vs baseline: 3.7174x; 3.7174x over previous
//
#include <hip/hip_runtime.h>

// GAT: N=4096, F_IN=128, F_HID=64, H=4, F_OUT=64, alpha=0.2
#define GN 4096
#define F_IN 128
#define F_HID 64
#define NHEADS 4
#define F_OUT 64
#define ALPHA 0.2f
#define MAX_DEG 256
#define NGEMM 512          // GEMM blocks in K1 (8 nodes each), placed FIRST

// workspace layout (bytes)
#define OFF_WH     0           // GN*256*4 = 4 MB   [i][head*64+f]
#define OFF_SRC1   4194304     // GN*4*4 = 64 KB    [i][head]  (float4 per node)
#define OFF_DST1   4259840     // GN*4*4 = 64 KB    [i][head]
#define OFF_WH2    4325376     // GN*64*4 = 1 MB
#define OFF_SRC2   5373952     // GN*4
#define OFF_DST2   5390336     // GN*4
#define OFF_CNT    5406720     // GN*4
#define OFF_IDX    5423104     // GN*MAX_DEG*4 = 4 MB

// ===== K1: [GEMM blocks 0..511] + [compaction blocks 512..4607, 1 row each] =====
__global__ __launch_bounds__(256) void prep_kernel(
        const float* __restrict__ adj, const float* __restrict__ x,
        const float* __restrict__ linW, const float* __restrict__ linb,
        const float* __restrict__ Wheads, const float* __restrict__ aheads,
        float* __restrict__ Wh, float* __restrict__ src1, float* __restrict__ dst1,
        int* __restrict__ cnt, int* __restrict__ idx) {
    __shared__ union {
        struct { int sidx[4][264]; int scnt[4]; } c;
        struct { float xs[8][128]; float hs[8][128]; } g;
    } sm;
    const int tid = threadIdx.x;
    const int wave = tid >> 6, lane = tid & 63;

    if (blockIdx.x >= NGEMM) {
        // ---- neighbor compaction, ONE ROW PER BLOCK (R5 proven shape) ----
        const int row = blockIdx.x - NGEMM;
        const float4* a4 = (const float4*)(adj + (size_t)row * GN) + wave * 256;
        int count = 0;
        #pragma unroll
        for (int it = 0; it < 4; ++it) {
            float4 v = a4[it * 64 + lane];
            bool b0 = v.x > 0.0f, b1 = v.y > 0.0f, b2 = v.z > 0.0f, b3 = v.w > 0.0f;
            unsigned long long m0 = __ballot(b0), m1 = __ballot(b1);
            unsigned long long m2 = __ballot(b2), m3 = __ballot(b3);
            int p0 = __builtin_amdgcn_mbcnt_hi((unsigned)(m0 >> 32), __builtin_amdgcn_mbcnt_lo((unsigned)m0, 0u));
            int p1 = __builtin_amdgcn_mbcnt_hi((unsigned)(m1 >> 32), __builtin_amdgcn_mbcnt_lo((unsigned)m1, 0u));
            int p2 = __builtin_amdgcn_mbcnt_hi((unsigned)(m2 >> 32), __builtin_amdgcn_mbcnt_lo((unsigned)m2, 0u));
            int p3 = __builtin_amdgcn_mbcnt_hi((unsigned)(m3 >> 32), __builtin_amdgcn_mbcnt_lo((unsigned)m3, 0u));
            int c0 = __popcll(m0), c1 = __popcll(m1), c2 = __popcll(m2), c3 = __popcll(m3);
            int col = wave * 1024 + it * 256 + lane * 4;
            int pos = count + p0;
            if (b0 && pos < 264) sm.c.sidx[wave][pos] = col;
            pos = count + c0 + p1;
            if (b1 && pos < 264) sm.c.sidx[wave][pos] = col + 1;
            pos = count + c0 + c1 + p2;
            if (b2 && pos < 264) sm.c.sidx[wave][pos] = col + 2;
            pos = count + c0 + c1 + c2 + p3;
            if (b3 && pos < 264) sm.c.sidx[wave][pos] = col + 3;
            count += c0 + c1 + c2 + c3;
        }
        if (lane == 0) sm.c.scnt[wave] = count;
        __syncthreads();
        int base = 0;
        #pragma unroll
        for (int w = 0; w < 3; ++w) base += (w < wave) ? sm.c.scnt[w] : 0;
        const int total = sm.c.scnt[0] + sm.c.scnt[1] + sm.c.scnt[2] + sm.c.scnt[3];
        const int cc = (total > MAX_DEG) ? MAX_DEG : total;
        int* outp = idx + (size_t)row * MAX_DEG;
        for (int t = lane; t < count; t += 64) {
            int pos = base + t;
            if (pos < MAX_DEG) outp[pos] = sm.c.sidx[wave][t];
        }
        if (tid < 4) {
            int pad = ((cc + 3) & ~3) - cc;
            if (tid < pad) outp[cc + tid] = 0;   // padded entries -> weight exactly 0
            if (tid == 0) cnt[row] = cc;
        }
        return;
    }

    // ---- fused GEMMs: h = x@linW+b ; Wh = h@W_heads ; src1/dst1 (8 nodes) ----
    const int i0 = blockIdx.x * 8;
    #pragma unroll
    for (int t = 0; t < 4; ++t) {
        int e = t * 256 + tid;
        sm.g.xs[e >> 7][e & 127] = x[(size_t)i0 * 128 + e];
    }
    __syncthreads();
    {
        const int k = tid & 127;
        const int n0 = tid >> 7;               // nodes {n0, n0+2, n0+4, n0+6}
        float bk = linb[k];
        float a0 = bk, a1 = bk, a2 = bk, a3 = bk;
        for (int j = 0; j < 128; ++j) {
            float w = linW[j * 128 + k];
            a0 += sm.g.xs[n0][j] * w;
            a1 += sm.g.xs[n0 + 2][j] * w;
            a2 += sm.g.xs[n0 + 4][j] * w;
            a3 += sm.g.xs[n0 + 6][j] * w;
        }
        sm.g.hs[n0][k] = a0; sm.g.hs[n0 + 2][k] = a1;
        sm.g.hs[n0 + 4][k] = a2; sm.g.hs[n0 + 6][k] = a3;
    }
    __syncthreads();
    {
        const int hd = tid >> 6, f = tid & 63;
        float acc[8] = {0, 0, 0, 0, 0, 0, 0, 0};
        const float* Wp = Wheads + (size_t)hd * F_IN * F_HID + f;
        for (int j = 0; j < 128; ++j) {
            float w = Wp[j * 64];
            #pragma unroll
            for (int n = 0; n < 8; ++n) acc[n] += sm.g.hs[n][j] * w;
        }
        const float as = aheads[hd * 128 + f];
        const float ad = aheads[hd * 128 + 64 + f];
        #pragma unroll
        for (int n = 0; n < 8; ++n) {
            Wh[(size_t)(i0 + n) * 256 + hd * 64 + f] = acc[n];
            float sv = acc[n] * as, dv = acc[n] * ad;
            #pragma unroll
            for (int o = 32; o > 0; o >>= 1) {
                sv += __shfl_xor(sv, o, 64);
                dv += __shfl_xor(dv, o, 64);
            }
            // interleaved [node][head] layout -> one float4 gather/neighbor in K2
            if (f == 0) { src1[(i0 + n) * 4 + hd] = sv; dst1[(i0 + n) * 4 + hd] = dv; }
        }
    }
}

// ===== K2: layer-1 attention (all 4 heads, wave/row) + Wend projection, hcat in LDS =====
__global__ __launch_bounds__(256) void attn_mid_kernel(
        const float* __restrict__ Wh, const float* __restrict__ src1,
        const float* __restrict__ dst1, const float* __restrict__ Wend,
        const float* __restrict__ aend, float* __restrict__ Wh2,
        float* __restrict__ src2, float* __restrict__ dst2,
        const int* __restrict__ cnt, const int* __restrict__ idx) {
    __shared__ float ps[4][1040];      // [wave][t*4+head]  (260 nbrs x 4 heads)
    __shared__ float hcat[4][256];     // per-wave concat row, consumed in-block
    const int wave = threadIdx.x >> 6;
    const int lane = threadIdx.x & 63;
    const int row  = blockIdx.x * 4 + wave;
    const int deg  = cnt[row];
    const int* nb  = idx + (size_t)row * MAX_DEG;
    const int nchunk = (deg + 63) >> 6;

    // phase 1: lanes over neighbors; ONE float4 gather per neighbor covers 4 heads
    const float4 s4 = ((const float4*)src1)[row];
    float4 ev[4];
    float4 m4 = make_float4(-1e30f, -1e30f, -1e30f, -1e30f);
    for (int c = 0; c < nchunk; ++c) {
        int t = c * 64 + lane;
        float4 e = make_float4(-1e30f, -1e30f, -1e30f, -1e30f);
        if (t < deg) {
            int j = nb[t];
            float4 d = ((const float4*)dst1)[j];
            e.x = s4.x + d.x; e.x = (e.x > 0.0f) ? e.x : ALPHA * e.x;
            e.y = s4.y + d.y; e.y = (e.y > 0.0f) ? e.y : ALPHA * e.y;
            e.z = s4.z + d.z; e.z = (e.z > 0.0f) ? e.z : ALPHA * e.z;
            e.w = s4.w + d.w; e.w = (e.w > 0.0f) ? e.w : ALPHA * e.w;
        }
        ev[c] = e;
        m4.x = fmaxf(m4.x, e.x); m4.y = fmaxf(m4.y, e.y);
        m4.z = fmaxf(m4.z, e.z); m4.w = fmaxf(m4.w, e.w);
    }
    #pragma unroll
    for (int o = 32; o > 0; o >>= 1) {
        m4.x = fmaxf(m4.x, __shfl_xor(m4.x, o, 64));
        m4.y = fmaxf(m4.y, __shfl_xor(m4.y, o, 64));
        m4.z = fmaxf(m4.z, __shfl_xor(m4.z, o, 64));
        m4.w = fmaxf(m4.w, __shfl_xor(m4.w, o, 64));
    }
    float4 l4 = make_float4(0.f, 0.f, 0.f, 0.f);
    for (int c = 0; c < nchunk; ++c) {
        ev[c].x = expf(ev[c].x - m4.x); l4.x += ev[c].x;
        ev[c].y = expf(ev[c].y - m4.y); l4.y += ev[c].y;
        ev[c].z = expf(ev[c].z - m4.z); l4.z += ev[c].z;
        ev[c].w = expf(ev[c].w - m4.w); l4.w += ev[c].w;
    }
    #pragma unroll
    for (int o = 32; o > 0; o >>= 1) {
        l4.x += __shfl_xor(l4.x, o, 64);
        l4.y += __shfl_xor(l4.y, o, 64);
        l4.z += __shfl_xor(l4.z, o, 64);
        l4.w += __shfl_xor(l4.w, o, 64);
    }
    const float4 inv = make_float4(1.f / l4.x, 1.f / l4.y, 1.f / l4.z, 1.f / l4.w);
    for (int c = 0; c < nchunk; ++c) {
        int t = c * 64 + lane;
        float4 p = make_float4(ev[c].x * inv.x, ev[c].y * inv.y,
                               ev[c].z * inv.z, ev[c].w * inv.w);
        ((float4*)&ps[wave][0])[t] = p;
    }

    // phase 2: lane covers head lane>>4, features 4*(lane&15)..+3; float4 gathers
    const int hl = lane >> 4;
    const float4* Wh4 = (const float4*)Wh;
    float4 acc = make_float4(0.f, 0.f, 0.f, 0.f);
    const int deg4 = (deg + 3) & ~3;
    for (int t = 0; t < deg4; t += 4) {
        int4 jj = *(const int4*)(nb + t);
        float p0 = ps[wave][(t    ) * 4 + hl];
        float p1 = ps[wave][(t + 1) * 4 + hl];
        float p2 = ps[wave][(t + 2) * 4 + hl];
        float p3 = ps[wave][(t + 3) * 4 + hl];
        float4 v0 = Wh4[(size_t)jj.x * 64 + lane];
        float4 v1 = Wh4[(size_t)jj.y * 64 + lane];
        float4 v2 = Wh4[(size_t)jj.z * 64 + lane];
        float4 v3 = Wh4[(size_t)jj.w * 64 + lane];
        acc.x += p0 * v0.x + p1 * v1.x + p2 * v2.x + p3 * v3.x;
        acc.y += p0 * v0.y + p1 * v1.y + p2 * v2.y + p3 * v3.y;
        acc.z += p0 * v0.z + p1 * v1.z + p2 * v2.z + p3 * v3.z;
        acc.w += p0 * v0.w + p1 * v1.w + p2 * v2.w + p3 * v3.w;
    }
    acc.x = (acc.x > 0.0f) ? acc.x : expm1f(acc.x);
    acc.y = (acc.y > 0.0f) ? acc.y : expm1f(acc.y);
    acc.z = (acc.z > 0.0f) ? acc.z : expm1f(acc.z);
    acc.w = (acc.w > 0.0f) ? acc.w : expm1f(acc.w);
    ((float4*)hcat[wave])[lane] = acc;         // stays in LDS (same wave consumes)

    // phase C: Wh2[row] = hcat[row] @ Wend ; src2/dst2
    float a0 = 0.0f, a1 = 0.0f;
    const float* Wp = Wend + lane;
    for (int j = 0; j < 256; j += 2) {
        a0 += hcat[wave][j] * Wp[j * 64];
        a1 += hcat[wave][j + 1] * Wp[(j + 1) * 64];
    }
    float aa = a0 + a1;
    Wh2[(size_t)row * 64 + lane] = aa;
    float s0 = aa * aend[lane], d0 = aa * aend[64 + lane];
    #pragma unroll
    for (int o = 32; o > 0; o >>= 1) {
        s0 += __shfl_xor(s0, o, 64); d0 += __shfl_xor(d0, o, 64);
    }
    if (lane == 0) { src2[row] = s0; dst2[row] = d0; }
}

// ===== K3: layer-2 attention + elu + final row softmax; wave per row =====
__global__ __launch_bounds__(256) void attn2_kernel(
        const float* __restrict__ Wh2, const float* __restrict__ src,
        const float* __restrict__ dst, const int* __restrict__ cnt,
        const int* __restrict__ idx, float* __restrict__ out) {
    const int wave = threadIdx.x >> 6;
    const int lane = threadIdx.x & 63;
    const int row  = blockIdx.x * 4 + wave;
    const int deg = cnt[row];
    const int* nb = idx + (size_t)row * MAX_DEG;
    const float s_i = src[row];

    float e[4];
    #pragma unroll
    for (int c = 0; c < 4; ++c) {
        int t = c * 64 + lane;
        float ev = -1e30f;
        if (t < deg) {
            int j = nb[t];
            ev = s_i + dst[j];
            ev = (ev > 0.0f) ? ev : ALPHA * ev;
        }
        e[c] = ev;
    }
    float m = fmaxf(fmaxf(e[0], e[1]), fmaxf(e[2], e[3]));
    #pragma unroll
    for (int o = 32; o > 0; o >>= 1) m = fmaxf(m, __shfl_xor(m, o, 64));
    float l = 0.0f;
    #pragma unroll
    for (int c = 0; c < 4; ++c) { e[c] = expf(e[c] - m); l += e[c]; }
    #pragma unroll
    for (int o = 32; o > 0; o >>= 1) l += __shfl_xor(l, o, 64);

    float accA = 0.0f, accB = 0.0f;
    const float* W2 = Wh2 + lane;
    #pragma unroll
    for (int c = 0; c < 4; ++c) {
        int base = c * 64;
        if (base >= deg) break;
        int nmax = deg - base; if (nmax > 64) nmax = 64;
        int n4 = (nmax + 3) & ~3;
        for (int t = 0; t < n4; t += 4) {
            float p0 = __shfl(e[c], t, 64);
            float p1 = __shfl(e[c], t + 1, 64);
            float p2 = __shfl(e[c], t + 2, 64);
            float p3 = __shfl(e[c], t + 3, 64);
            int4 jj = *(const int4*)(nb + base + t);
            accA += p0 * W2[(size_t)jj.x * 64];
            accB += p1 * W2[(size_t)jj.y * 64];
            accA += p2 * W2[(size_t)jj.z * 64];
            accB += p3 * W2[(size_t)jj.w * 64];
        }
    }
    float v = (accA + accB) / l;
    v = (v > 0.0f) ? v : expm1f(v);    // elu

    float mm = v;
    #pragma unroll
    for (int o = 32; o > 0; o >>= 1) mm = fmaxf(mm, __shfl_xor(mm, o, 64));
    float ee = expf(v - mm);
    float ss = ee;
    #pragma unroll
    for (int o = 32; o > 0; o >>= 1) ss += __shfl_xor(ss, o, 64);
    out[(size_t)row * F_OUT + lane] = ee / ss;
}

extern "C" void kernel_launch(void* const* d_in, const int* in_sizes, int n_in,
                              void* d_out, int out_size, void* d_ws, size_t ws_size,
                              hipStream_t stream) {
    const float* x      = (const float*)d_in[0];
    const float* adj    = (const float*)d_in[1];
    const float* lin_W  = (const float*)d_in[2];
    const float* lin_b  = (const float*)d_in[3];
    const float* Wheads = (const float*)d_in[4];
    const float* aheads = (const float*)d_in[5];
    const float* Wend   = (const float*)d_in[6];
    const float* aend   = (const float*)d_in[7];
    float* out = (float*)d_out;

    char* ws = (char*)d_ws;
    float* Wh   = (float*)(ws + OFF_WH);
    float* src1 = (float*)(ws + OFF_SRC1);
    float* dst1 = (float*)(ws + OFF_DST1);
    float* Wh2  = (float*)(ws + OFF_WH2);
    float* src2 = (float*)(ws + OFF_SRC2);
    float* dst2 = (float*)(ws + OFF_DST2);
    int*   cnt  = (int*)(ws + OFF_CNT);
    int*   nidx = (int*)(ws + OFF_IDX);

    prep_kernel<<<NGEMM + GN, 256, 0, stream>>>(adj, x, lin_W, lin_b, Wheads, aheads,
                                                Wh, src1, dst1, cnt, nidx);
    attn_mid_kernel<<<GN / 4, 256, 0, stream>>>(Wh, src1, dst1, Wend, aend,
                                                Wh2, src2, dst2, cnt, nidx);
    attn2_kernel<<<GN / 4, 256, 0, stream>>>(Wh2, src2, dst2, cnt, nidx, out);
}

// Round 9
// 56.269 us; speedup vs baseline: 3.8966x; 1.0482x over previous
//
#include <hip/hip_runtime.h>

// GAT: N=4096, F_IN=128, F_HID=64, H=4, F_OUT=64, alpha=0.2
#define GN 4096
#define F_IN 128
#define F_HID 64
#define NHEADS 4
#define F_OUT 64
#define ALPHA 0.2f
#define MAX_DEG 256
#define NGEMM 512          // GEMM blocks in K1 (8 nodes each), placed FIRST

// workspace layout (bytes)
#define OFF_WH     0           // GN*256*4 = 4 MB   [i][head*64+f]
#define OFF_SRC1   4194304     // GN*4*4             [i][head] float4/node
#define OFF_DST1   4259840     // GN*4*4
#define OFF_WH2    4325376     // GN*64*4 = 1 MB
#define OFF_SRC2   5373952     // GN*4
#define OFF_DST2   5390336     // GN*4
#define OFF_CNT    5406720     // GN*4
#define OFF_IDX    5423104     // GN*MAX_DEG*4 = 4 MB

// ===== K1: [GEMM blocks 0..511] + [compaction blocks 512..4607, 1 row each] =====
__global__ __launch_bounds__(256) void prep_kernel(
        const float* __restrict__ adj, const float* __restrict__ x,
        const float* __restrict__ linW, const float* __restrict__ linb,
        const float* __restrict__ Wheads, const float* __restrict__ aheads,
        float* __restrict__ Wh, float* __restrict__ src1, float* __restrict__ dst1,
        int* __restrict__ cnt, int* __restrict__ idx) {
    __shared__ union {
        struct { int sidx[4][264]; int scnt[4]; } c;
        struct { float xs[8][128]; float hs[8][128]; } g;
    } sm;
    const int tid = threadIdx.x;
    const int wave = tid >> 6, lane = tid & 63;

    if (blockIdx.x >= NGEMM) {
        // ---- compaction: lane covers 16 CONTIGUOUS cols; loads all issued up front ----
        const int row = blockIdx.x - NGEMM;
        const float4* a4 = (const float4*)(adj + (size_t)row * GN) + wave * 256 + lane * 4;
        float4 v0 = a4[0], v1 = a4[1], v2 = a4[2], v3 = a4[3];
        unsigned msk = 0;
        msk |= (v0.x > 0.0f) ? 1u : 0u;         msk |= (v0.y > 0.0f) ? 2u : 0u;
        msk |= (v0.z > 0.0f) ? 4u : 0u;         msk |= (v0.w > 0.0f) ? 8u : 0u;
        msk |= (v1.x > 0.0f) ? 16u : 0u;        msk |= (v1.y > 0.0f) ? 32u : 0u;
        msk |= (v1.z > 0.0f) ? 64u : 0u;        msk |= (v1.w > 0.0f) ? 128u : 0u;
        msk |= (v2.x > 0.0f) ? 256u : 0u;       msk |= (v2.y > 0.0f) ? 512u : 0u;
        msk |= (v2.z > 0.0f) ? 1024u : 0u;      msk |= (v2.w > 0.0f) ? 2048u : 0u;
        msk |= (v3.x > 0.0f) ? 4096u : 0u;      msk |= (v3.y > 0.0f) ? 8192u : 0u;
        msk |= (v3.z > 0.0f) ? 16384u : 0u;     msk |= (v3.w > 0.0f) ? 32768u : 0u;
        const int c = __popc(msk);
        // inclusive prefix-scan of c over 64 lanes (6 shuffle steps)
        int inc = c;
        #pragma unroll
        for (int o = 1; o < 64; o <<= 1) {
            int n = __shfl_up(inc, o, 64);
            if (lane >= o) inc += n;
        }
        int p = inc - c;                        // exclusive prefix
        const int colbase = wave * 1024 + lane * 16;
        #pragma unroll
        for (int b = 0; b < 16; ++b) {
            if (msk & (1u << b)) {
                if (p < 264) sm.c.sidx[wave][p] = colbase + b;
                ++p;
            }
        }
        if (lane == 63) sm.c.scnt[wave] = inc;  // wave total
        __syncthreads();
        int base = 0;
        #pragma unroll
        for (int w = 0; w < 3; ++w) base += (w < wave) ? sm.c.scnt[w] : 0;
        const int wcount = sm.c.scnt[wave];
        const int total = sm.c.scnt[0] + sm.c.scnt[1] + sm.c.scnt[2] + sm.c.scnt[3];
        const int cc = (total > MAX_DEG) ? MAX_DEG : total;
        int* outp = idx + (size_t)row * MAX_DEG;
        for (int t = lane; t < wcount; t += 64) {
            int pos = base + t;
            if (pos < MAX_DEG) outp[pos] = sm.c.sidx[wave][t];
        }
        if (tid < 8) {
            int pad = ((cc + 7) & ~7) - cc;     // pad to x8 for ILP-8 gather loops
            if (tid < pad) outp[cc + tid] = 0;  // padded entries -> weight exactly 0
            if (tid == 0) cnt[row] = cc;
        }
        return;
    }

    // ---- fused GEMMs: h = x@linW+b ; Wh = h@W_heads ; src1/dst1 (8 nodes) ----
    const int i0 = blockIdx.x * 8;
    #pragma unroll
    for (int t = 0; t < 4; ++t) {
        int e = t * 256 + tid;
        sm.g.xs[e >> 7][e & 127] = x[(size_t)i0 * 128 + e];
    }
    __syncthreads();
    {
        const int k = tid & 127;
        const int n0 = tid >> 7;               // nodes {n0, n0+2, n0+4, n0+6}
        float bk = linb[k];
        float a0 = bk, a1 = bk, a2 = bk, a3 = bk;
        for (int j = 0; j < 128; ++j) {
            float w = linW[j * 128 + k];
            a0 += sm.g.xs[n0][j] * w;
            a1 += sm.g.xs[n0 + 2][j] * w;
            a2 += sm.g.xs[n0 + 4][j] * w;
            a3 += sm.g.xs[n0 + 6][j] * w;
        }
        sm.g.hs[n0][k] = a0; sm.g.hs[n0 + 2][k] = a1;
        sm.g.hs[n0 + 4][k] = a2; sm.g.hs[n0 + 6][k] = a3;
    }
    __syncthreads();
    {
        const int hd = tid >> 6, f = tid & 63;
        float acc[8] = {0, 0, 0, 0, 0, 0, 0, 0};
        const float* Wp = Wheads + (size_t)hd * F_IN * F_HID + f;
        for (int j = 0; j < 128; ++j) {
            float w = Wp[j * 64];
            #pragma unroll
            for (int n = 0; n < 8; ++n) acc[n] += sm.g.hs[n][j] * w;
        }
        const float as = aheads[hd * 128 + f];
        const float ad = aheads[hd * 128 + 64 + f];
        #pragma unroll
        for (int n = 0; n < 8; ++n) {
            Wh[(size_t)(i0 + n) * 256 + hd * 64 + f] = acc[n];
            float sv = acc[n] * as, dv = acc[n] * ad;
            #pragma unroll
            for (int o = 32; o > 0; o >>= 1) {
                sv += __shfl_xor(sv, o, 64);
                dv += __shfl_xor(dv, o, 64);
            }
            if (f == 0) { src1[(i0 + n) * 4 + hd] = sv; dst1[(i0 + n) * 4 + hd] = dv; }
        }
    }
}

// ===== K2: layer-1 attention (all heads, wave/row) + Wend projection, hcat in LDS =====
__global__ __launch_bounds__(256) void attn_mid_kernel(
        const float* __restrict__ Wh, const float* __restrict__ src1,
        const float* __restrict__ dst1, const float* __restrict__ Wend,
        const float* __restrict__ aend, float* __restrict__ Wh2,
        float* __restrict__ src2, float* __restrict__ dst2,
        const int* __restrict__ cnt, const int* __restrict__ idx) {
    __shared__ float ps[4][1040];      // [wave][t*4+head]
    __shared__ float hcat[4][256];     // per-wave concat row, consumed in-block
    const int wave = threadIdx.x >> 6;
    const int lane = threadIdx.x & 63;
    const int row  = blockIdx.x * 4 + wave;
    const int deg  = cnt[row];
    const int* nb  = idx + (size_t)row * MAX_DEG;
    const int nchunk = (deg + 63) >> 6;

    // phase 1: lanes over neighbors; one float4 gather covers all 4 heads
    const float4 s4 = ((const float4*)src1)[row];
    float4 ev[4];
    float4 m4 = make_float4(-1e30f, -1e30f, -1e30f, -1e30f);
    for (int c = 0; c < nchunk; ++c) {
        int t = c * 64 + lane;
        float4 e = make_float4(-1e30f, -1e30f, -1e30f, -1e30f);
        if (t < deg) {
            int j = nb[t];
            float4 d = ((const float4*)dst1)[j];
            e.x = s4.x + d.x; e.x = (e.x > 0.0f) ? e.x : ALPHA * e.x;
            e.y = s4.y + d.y; e.y = (e.y > 0.0f) ? e.y : ALPHA * e.y;
            e.z = s4.z + d.z; e.z = (e.z > 0.0f) ? e.z : ALPHA * e.z;
            e.w = s4.w + d.w; e.w = (e.w > 0.0f) ? e.w : ALPHA * e.w;
        }
        ev[c] = e;
        m4.x = fmaxf(m4.x, e.x); m4.y = fmaxf(m4.y, e.y);
        m4.z = fmaxf(m4.z, e.z); m4.w = fmaxf(m4.w, e.w);
    }
    #pragma unroll
    for (int o = 32; o > 0; o >>= 1) {
        m4.x = fmaxf(m4.x, __shfl_xor(m4.x, o, 64));
        m4.y = fmaxf(m4.y, __shfl_xor(m4.y, o, 64));
        m4.z = fmaxf(m4.z, __shfl_xor(m4.z, o, 64));
        m4.w = fmaxf(m4.w, __shfl_xor(m4.w, o, 64));
    }
    float4 l4 = make_float4(0.f, 0.f, 0.f, 0.f);
    for (int c = 0; c < nchunk; ++c) {
        ev[c].x = expf(ev[c].x - m4.x); l4.x += ev[c].x;
        ev[c].y = expf(ev[c].y - m4.y); l4.y += ev[c].y;
        ev[c].z = expf(ev[c].z - m4.z); l4.z += ev[c].z;
        ev[c].w = expf(ev[c].w - m4.w); l4.w += ev[c].w;
    }
    #pragma unroll
    for (int o = 32; o > 0; o >>= 1) {
        l4.x += __shfl_xor(l4.x, o, 64);
        l4.y += __shfl_xor(l4.y, o, 64);
        l4.z += __shfl_xor(l4.z, o, 64);
        l4.w += __shfl_xor(l4.w, o, 64);
    }
    const float4 inv = make_float4(1.f / l4.x, 1.f / l4.y, 1.f / l4.z, 1.f / l4.w);
    for (int c = 0; c < nchunk; ++c) {
        int t = c * 64 + lane;
        float4 p = make_float4(ev[c].x * inv.x, ev[c].y * inv.y,
                               ev[c].z * inv.z, ev[c].w * inv.w);
        ((float4*)&ps[wave][0])[t] = p;
    }

    // phase 2: ILP-8 float4 gathers (nbr list padded to x8)
    const int hl = lane >> 4;
    const float4* Wh4 = (const float4*)Wh;
    float4 acc = make_float4(0.f, 0.f, 0.f, 0.f);
    const int deg8 = (deg + 7) & ~7;
    for (int t = 0; t < deg8; t += 8) {
        int4 ja = *(const int4*)(nb + t);
        int4 jb = *(const int4*)(nb + t + 4);
        float4 w0 = Wh4[(size_t)ja.x * 64 + lane];
        float4 w1 = Wh4[(size_t)ja.y * 64 + lane];
        float4 w2 = Wh4[(size_t)ja.z * 64 + lane];
        float4 w3 = Wh4[(size_t)ja.w * 64 + lane];
        float4 w4 = Wh4[(size_t)jb.x * 64 + lane];
        float4 w5 = Wh4[(size_t)jb.y * 64 + lane];
        float4 w6 = Wh4[(size_t)jb.z * 64 + lane];
        float4 w7 = Wh4[(size_t)jb.w * 64 + lane];
        float p0 = ps[wave][(t    ) * 4 + hl], p1 = ps[wave][(t + 1) * 4 + hl];
        float p2 = ps[wave][(t + 2) * 4 + hl], p3 = ps[wave][(t + 3) * 4 + hl];
        float p4 = ps[wave][(t + 4) * 4 + hl], p5 = ps[wave][(t + 5) * 4 + hl];
        float p6 = ps[wave][(t + 6) * 4 + hl], p7 = ps[wave][(t + 7) * 4 + hl];
        acc.x += p0 * w0.x + p1 * w1.x + p2 * w2.x + p3 * w3.x
               + p4 * w4.x + p5 * w5.x + p6 * w6.x + p7 * w7.x;
        acc.y += p0 * w0.y + p1 * w1.y + p2 * w2.y + p3 * w3.y
               + p4 * w4.y + p5 * w5.y + p6 * w6.y + p7 * w7.y;
        acc.z += p0 * w0.z + p1 * w1.z + p2 * w2.z + p3 * w3.z
               + p4 * w4.z + p5 * w5.z + p6 * w6.z + p7 * w7.z;
        acc.w += p0 * w0.w + p1 * w1.w + p2 * w2.w + p3 * w3.w
               + p4 * w4.w + p5 * w5.w + p6 * w6.w + p7 * w7.w;
    }
    acc.x = (acc.x > 0.0f) ? acc.x : expm1f(acc.x);
    acc.y = (acc.y > 0.0f) ? acc.y : expm1f(acc.y);
    acc.z = (acc.z > 0.0f) ? acc.z : expm1f(acc.z);
    acc.w = (acc.w > 0.0f) ? acc.w : expm1f(acc.w);
    ((float4*)hcat[wave])[lane] = acc;         // stays in LDS (same wave consumes)

    // phase C: Wh2[row] = hcat[row] @ Wend ; src2/dst2  (4 accumulators)
    float a0 = 0.f, a1 = 0.f, a2 = 0.f, a3 = 0.f;
    const float* Wp = Wend + lane;
    #pragma unroll 4
    for (int j = 0; j < 256; j += 4) {
        a0 += hcat[wave][j    ] * Wp[(j    ) * 64];
        a1 += hcat[wave][j + 1] * Wp[(j + 1) * 64];
        a2 += hcat[wave][j + 2] * Wp[(j + 2) * 64];
        a3 += hcat[wave][j + 3] * Wp[(j + 3) * 64];
    }
    float aa = (a0 + a1) + (a2 + a3);
    Wh2[(size_t)row * 64 + lane] = aa;
    float s0 = aa * aend[lane], d0 = aa * aend[64 + lane];
    #pragma unroll
    for (int o = 32; o > 0; o >>= 1) {
        s0 += __shfl_xor(s0, o, 64); d0 += __shfl_xor(d0, o, 64);
    }
    if (lane == 0) { src2[row] = s0; dst2[row] = d0; }
}

// ===== K3: layer-2 attention + elu + final row softmax; wave per row; ILP-8 =====
__global__ __launch_bounds__(256) void attn2_kernel(
        const float* __restrict__ Wh2, const float* __restrict__ src,
        const float* __restrict__ dst, const int* __restrict__ cnt,
        const int* __restrict__ idx, float* __restrict__ out) {
    const int wave = threadIdx.x >> 6;
    const int lane = threadIdx.x & 63;
    const int row  = blockIdx.x * 4 + wave;
    const int deg = cnt[row];
    const int* nb = idx + (size_t)row * MAX_DEG;
    const float s_i = src[row];

    float e[4];
    #pragma unroll
    for (int c = 0; c < 4; ++c) {
        int t = c * 64 + lane;
        float ev = -1e30f;
        if (t < deg) {
            int j = nb[t];
            ev = s_i + dst[j];
            ev = (ev > 0.0f) ? ev : ALPHA * ev;
        }
        e[c] = ev;
    }
    float m = fmaxf(fmaxf(e[0], e[1]), fmaxf(e[2], e[3]));
    #pragma unroll
    for (int o = 32; o > 0; o >>= 1) m = fmaxf(m, __shfl_xor(m, o, 64));
    float l = 0.0f;
    #pragma unroll
    for (int c = 0; c < 4; ++c) { e[c] = expf(e[c] - m); l += e[c]; }
    #pragma unroll
    for (int o = 32; o > 0; o >>= 1) l += __shfl_xor(l, o, 64);

    float accA = 0.0f, accB = 0.0f;
    const float* W2 = Wh2 + lane;
    #pragma unroll
    for (int c = 0; c < 4; ++c) {
        int base = c * 64;
        if (base >= deg) break;
        int nmax = deg - base; if (nmax > 64) nmax = 64;
        int n8 = (nmax + 7) & ~7;
        for (int t = 0; t < n8; t += 8) {
            int4 ja = *(const int4*)(nb + base + t);
            int4 jb = *(const int4*)(nb + base + t + 4);
            float w0 = W2[(size_t)ja.x * 64];
            float w1 = W2[(size_t)ja.y * 64];
            float w2 = W2[(size_t)ja.z * 64];
            float w3 = W2[(size_t)ja.w * 64];
            float w4 = W2[(size_t)jb.x * 64];
            float w5 = W2[(size_t)jb.y * 64];
            float w6 = W2[(size_t)jb.z * 64];
            float w7 = W2[(size_t)jb.w * 64];
            float p0 = __shfl(e[c], t, 64),     p1 = __shfl(e[c], t + 1, 64);
            float p2 = __shfl(e[c], t + 2, 64), p3 = __shfl(e[c], t + 3, 64);
            float p4 = __shfl(e[c], t + 4, 64), p5 = __shfl(e[c], t + 5, 64);
            float p6 = __shfl(e[c], t + 6, 64), p7 = __shfl(e[c], t + 7, 64);
            accA += p0 * w0 + p2 * w2 + p4 * w4 + p6 * w6;
            accB += p1 * w1 + p3 * w3 + p5 * w5 + p7 * w7;
        }
    }
    float v = (accA + accB) / l;
    v = (v > 0.0f) ? v : expm1f(v);    // elu

    float mm = v;
    #pragma unroll
    for (int o = 32; o > 0; o >>= 1) mm = fmaxf(mm, __shfl_xor(mm, o, 64));
    float ee = expf(v - mm);
    float ss = ee;
    #pragma unroll
    for (int o = 32; o > 0; o >>= 1) ss += __shfl_xor(ss, o, 64);
    out[(size_t)row * F_OUT + lane] = ee / ss;
}

extern "C" void kernel_launch(void* const* d_in, const int* in_sizes, int n_in,
                              void* d_out, int out_size, void* d_ws, size_t ws_size,
                              hipStream_t stream) {
    const float* x      = (const float*)d_in[0];
    const float* adj    = (const float*)d_in[1];
    const float* lin_W  = (const float*)d_in[2];
    const float* lin_b  = (const float*)d_in[3];
    const float* Wheads = (const float*)d_in[4];
    const float* aheads = (const float*)d_in[5];
    const float* Wend   = (const float*)d_in[6];
    const float* aend   = (const float*)d_in[7];
    float* out = (float*)d_out;

    char* ws = (char*)d_ws;
    float* Wh   = (float*)(ws + OFF_WH);
    float* src1 = (float*)(ws + OFF_SRC1);
    float* dst1 = (float*)(ws + OFF_DST1);
    float* Wh2  = (float*)(ws + OFF_WH2);
    float* src2 = (float*)(ws + OFF_SRC2);
    float* dst2 = (float*)(ws + OFF_DST2);
    int*   cnt  = (int*)(ws + OFF_CNT);
    int*   nidx = (int*)(ws + OFF_IDX);

    prep_kernel<<<NGEMM + GN, 256, 0, stream>>>(adj, x, lin_W, lin_b, Wheads, aheads,
                                                Wh, src1, dst1, cnt, nidx);
    attn_mid_kernel<<<GN / 4, 256, 0, stream>>>(Wh, src1, dst1, Wend, aend,
                                                Wh2, src2, dst2, cnt, nidx);
    attn2_kernel<<<GN / 4, 256, 0, stream>>>(Wh2, src2, dst2, cnt, nidx, out);
}

// Round 10
// 56.156 us; speedup vs baseline: 3.9044x; 1.0020x over previous
//
#include <hip/hip_runtime.h>

// GAT: N=4096, F_IN=128, F_HID=64, H=4, F_OUT=64, alpha=0.2
#define GN 4096
#define F_IN 128
#define F_HID 64
#define NHEADS 4
#define F_OUT 64
#define ALPHA 0.2f
#define MAX_DEG 256
#define NGEMM 512          // GEMM blocks in K1 (8 nodes each), placed FIRST

// workspace layout (bytes)
#define OFF_WH     0           // GN*256*4 = 4 MB   [i][head*64+f]
#define OFF_SRC1   4194304     // GN*4*4             [i][head] float4/node
#define OFF_DST1   4259840     // GN*4*4
#define OFF_WH2    4325376     // GN*64*4 = 1 MB
#define OFF_SRC2   5373952     // GN*4
#define OFF_DST2   5390336     // GN*4
#define OFF_CNT    5406720     // GN*4
#define OFF_IDX    5423104     // GN*MAX_DEG*4 = 4 MB

// ===== K1: [GEMM blocks 0..511] + [compaction blocks 512..4607, 1 row each] =====
__global__ __launch_bounds__(256) void prep_kernel(
        const float* __restrict__ adj, const float* __restrict__ x,
        const float* __restrict__ linW, const float* __restrict__ linb,
        const float* __restrict__ Wheads, const float* __restrict__ aheads,
        float* __restrict__ Wh, float* __restrict__ src1, float* __restrict__ dst1,
        int* __restrict__ cnt, int* __restrict__ idx) {
    __shared__ union {
        struct { int sidx[4][264]; int scnt[4]; } c;
        struct { float xs[8][128]; float hs[8][128]; } g;
    } sm;
    const int tid = threadIdx.x;
    const int wave = tid >> 6, lane = tid & 63;

    if (blockIdx.x >= NGEMM) {
        // ---- compaction: lane covers 16 CONTIGUOUS cols; all loads issued up front ----
        const int row = blockIdx.x - NGEMM;
        const float4* a4 = (const float4*)(adj + (size_t)row * GN) + wave * 256 + lane * 4;
        float4 v0 = a4[0], v1 = a4[1], v2 = a4[2], v3 = a4[3];
        unsigned msk = 0;
        msk |= (v0.x > 0.0f) ? 1u : 0u;         msk |= (v0.y > 0.0f) ? 2u : 0u;
        msk |= (v0.z > 0.0f) ? 4u : 0u;         msk |= (v0.w > 0.0f) ? 8u : 0u;
        msk |= (v1.x > 0.0f) ? 16u : 0u;        msk |= (v1.y > 0.0f) ? 32u : 0u;
        msk |= (v1.z > 0.0f) ? 64u : 0u;        msk |= (v1.w > 0.0f) ? 128u : 0u;
        msk |= (v2.x > 0.0f) ? 256u : 0u;       msk |= (v2.y > 0.0f) ? 512u : 0u;
        msk |= (v2.z > 0.0f) ? 1024u : 0u;      msk |= (v2.w > 0.0f) ? 2048u : 0u;
        msk |= (v3.x > 0.0f) ? 4096u : 0u;      msk |= (v3.y > 0.0f) ? 8192u : 0u;
        msk |= (v3.z > 0.0f) ? 16384u : 0u;     msk |= (v3.w > 0.0f) ? 32768u : 0u;
        const int c = __popc(msk);
        int inc = c;
        #pragma unroll
        for (int o = 1; o < 64; o <<= 1) {
            int n = __shfl_up(inc, o, 64);
            if (lane >= o) inc += n;
        }
        int p = inc - c;                        // exclusive prefix
        const int colbase = wave * 1024 + lane * 16;
        #pragma unroll
        for (int b = 0; b < 16; ++b) {
            if (msk & (1u << b)) {
                if (p < 264) sm.c.sidx[wave][p] = colbase + b;
                ++p;
            }
        }
        if (lane == 63) sm.c.scnt[wave] = inc;
        __syncthreads();
        int base = 0;
        #pragma unroll
        for (int w = 0; w < 3; ++w) base += (w < wave) ? sm.c.scnt[w] : 0;
        const int wcount = sm.c.scnt[wave];
        const int total = sm.c.scnt[0] + sm.c.scnt[1] + sm.c.scnt[2] + sm.c.scnt[3];
        const int cc = (total > MAX_DEG) ? MAX_DEG : total;
        int* outp = idx + (size_t)row * MAX_DEG;
        for (int t = lane; t < wcount; t += 64) {
            int pos = base + t;
            if (pos < MAX_DEG) outp[pos] = sm.c.sidx[wave][t];
        }
        if (tid < 16) {
            int pad = ((cc + 15) & ~15) - cc;   // pad to x16 for ILP-16 gather loops
            if (tid < pad) outp[cc + tid] = 0;  // padded entries -> weight exactly 0
            if (tid == 0) cnt[row] = cc;
        }
        return;
    }

    // ---- fused GEMMs: h = x@linW+b ; Wh = h@W_heads ; src1/dst1 (8 nodes) ----
    const int i0 = blockIdx.x * 8;
    #pragma unroll
    for (int t = 0; t < 4; ++t) {
        int e = t * 256 + tid;
        sm.g.xs[e >> 7][e & 127] = x[(size_t)i0 * 128 + e];
    }
    __syncthreads();
    {
        const int k = tid & 127;
        const int n0 = tid >> 7;
        float bk = linb[k];
        float a0 = bk, a1 = bk, a2 = bk, a3 = bk;
        for (int j = 0; j < 128; ++j) {
            float w = linW[j * 128 + k];
            a0 += sm.g.xs[n0][j] * w;
            a1 += sm.g.xs[n0 + 2][j] * w;
            a2 += sm.g.xs[n0 + 4][j] * w;
            a3 += sm.g.xs[n0 + 6][j] * w;
        }
        sm.g.hs[n0][k] = a0; sm.g.hs[n0 + 2][k] = a1;
        sm.g.hs[n0 + 4][k] = a2; sm.g.hs[n0 + 6][k] = a3;
    }
    __syncthreads();
    {
        const int hd = tid >> 6, f = tid & 63;
        float acc[8] = {0, 0, 0, 0, 0, 0, 0, 0};
        const float* Wp = Wheads + (size_t)hd * F_IN * F_HID + f;
        for (int j = 0; j < 128; ++j) {
            float w = Wp[j * 64];
            #pragma unroll
            for (int n = 0; n < 8; ++n) acc[n] += sm.g.hs[n][j] * w;
        }
        const float as = aheads[hd * 128 + f];
        const float ad = aheads[hd * 128 + 64 + f];
        #pragma unroll
        for (int n = 0; n < 8; ++n) {
            Wh[(size_t)(i0 + n) * 256 + hd * 64 + f] = acc[n];
            float sv = acc[n] * as, dv = acc[n] * ad;
            #pragma unroll
            for (int o = 32; o > 0; o >>= 1) {
                sv += __shfl_xor(sv, o, 64);
                dv += __shfl_xor(dv, o, 64);
            }
            if (f == 0) { src1[(i0 + n) * 4 + hd] = sv; dst1[(i0 + n) * 4 + hd] = dv; }
        }
    }
}

// ===== K2: layer-1 attention (all heads, wave/row) + LDS-staged Wend projection =====
__global__ __launch_bounds__(256) void attn_mid_kernel(
        const float* __restrict__ Wh, const float* __restrict__ src1,
        const float* __restrict__ dst1, const float* __restrict__ Wend,
        const float* __restrict__ aend, float* __restrict__ Wh2,
        float* __restrict__ src2, float* __restrict__ dst2,
        const int* __restrict__ cnt, const int* __restrict__ idx) {
    __shared__ union {
        float ps[4][1040];             // [wave][t*4+head]  (phase 1/2)
        float wtile[32][64];           // staged Wend tile   (phase C)
    } u;
    __shared__ float hcat[4][256];     // per-wave concat row, consumed in-block
    const int wave = threadIdx.x >> 6;
    const int lane = threadIdx.x & 63;
    const int tid  = threadIdx.x;
    const int row  = blockIdx.x * 4 + wave;
    const int deg  = cnt[row];
    const int* nb  = idx + (size_t)row * MAX_DEG;
    const int nchunk = (deg + 63) >> 6;

    // phase 1: lanes over neighbors; one float4 gather covers all 4 heads
    const float4 s4 = ((const float4*)src1)[row];
    float4 ev[4];
    float4 m4 = make_float4(-1e30f, -1e30f, -1e30f, -1e30f);
    for (int c = 0; c < nchunk; ++c) {
        int t = c * 64 + lane;
        float4 e = make_float4(-1e30f, -1e30f, -1e30f, -1e30f);
        if (t < deg) {
            int j = nb[t];
            float4 d = ((const float4*)dst1)[j];
            e.x = s4.x + d.x; e.x = (e.x > 0.0f) ? e.x : ALPHA * e.x;
            e.y = s4.y + d.y; e.y = (e.y > 0.0f) ? e.y : ALPHA * e.y;
            e.z = s4.z + d.z; e.z = (e.z > 0.0f) ? e.z : ALPHA * e.z;
            e.w = s4.w + d.w; e.w = (e.w > 0.0f) ? e.w : ALPHA * e.w;
        }
        ev[c] = e;
        m4.x = fmaxf(m4.x, e.x); m4.y = fmaxf(m4.y, e.y);
        m4.z = fmaxf(m4.z, e.z); m4.w = fmaxf(m4.w, e.w);
    }
    #pragma unroll
    for (int o = 32; o > 0; o >>= 1) {
        m4.x = fmaxf(m4.x, __shfl_xor(m4.x, o, 64));
        m4.y = fmaxf(m4.y, __shfl_xor(m4.y, o, 64));
        m4.z = fmaxf(m4.z, __shfl_xor(m4.z, o, 64));
        m4.w = fmaxf(m4.w, __shfl_xor(m4.w, o, 64));
    }
    float4 l4 = make_float4(0.f, 0.f, 0.f, 0.f);
    for (int c = 0; c < nchunk; ++c) {
        ev[c].x = expf(ev[c].x - m4.x); l4.x += ev[c].x;
        ev[c].y = expf(ev[c].y - m4.y); l4.y += ev[c].y;
        ev[c].z = expf(ev[c].z - m4.z); l4.z += ev[c].z;
        ev[c].w = expf(ev[c].w - m4.w); l4.w += ev[c].w;
    }
    #pragma unroll
    for (int o = 32; o > 0; o >>= 1) {
        l4.x += __shfl_xor(l4.x, o, 64);
        l4.y += __shfl_xor(l4.y, o, 64);
        l4.z += __shfl_xor(l4.z, o, 64);
        l4.w += __shfl_xor(l4.w, o, 64);
    }
    const float4 inv = make_float4(1.f / l4.x, 1.f / l4.y, 1.f / l4.z, 1.f / l4.w);
    for (int c = 0; c < nchunk; ++c) {
        int t = c * 64 + lane;
        float4 p = make_float4(ev[c].x * inv.x, ev[c].y * inv.y,
                               ev[c].z * inv.z, ev[c].w * inv.w);
        ((float4*)&u.ps[wave][0])[t] = p;
    }

    // phase 2: ILP-16 float4 gathers (nbr list padded to x16)
    const int hl = lane >> 4;
    const float4* Wh4 = (const float4*)Wh;
    float4 acc = make_float4(0.f, 0.f, 0.f, 0.f);
    const int deg16 = (deg + 15) & ~15;
    for (int t = 0; t < deg16; t += 16) {
        int4 ja = *(const int4*)(nb + t);
        int4 jb = *(const int4*)(nb + t + 4);
        int4 jc = *(const int4*)(nb + t + 8);
        int4 jd = *(const int4*)(nb + t + 12);
        float4 w0 = Wh4[(size_t)ja.x * 64 + lane];
        float4 w1 = Wh4[(size_t)ja.y * 64 + lane];
        float4 w2 = Wh4[(size_t)ja.z * 64 + lane];
        float4 w3 = Wh4[(size_t)ja.w * 64 + lane];
        float4 w4 = Wh4[(size_t)jb.x * 64 + lane];
        float4 w5 = Wh4[(size_t)jb.y * 64 + lane];
        float4 w6 = Wh4[(size_t)jb.z * 64 + lane];
        float4 w7 = Wh4[(size_t)jb.w * 64 + lane];
        float4 w8 = Wh4[(size_t)jc.x * 64 + lane];
        float4 w9 = Wh4[(size_t)jc.y * 64 + lane];
        float4 wa = Wh4[(size_t)jc.z * 64 + lane];
        float4 wb = Wh4[(size_t)jc.w * 64 + lane];
        float4 wc = Wh4[(size_t)jd.x * 64 + lane];
        float4 wd = Wh4[(size_t)jd.y * 64 + lane];
        float4 we = Wh4[(size_t)jd.z * 64 + lane];
        float4 wf = Wh4[(size_t)jd.w * 64 + lane];
        const float* pp = &u.ps[wave][t * 4 + hl];
        float p0 = pp[0],  p1 = pp[4],  p2 = pp[8],  p3 = pp[12];
        float p4 = pp[16], p5 = pp[20], p6 = pp[24], p7 = pp[28];
        float p8 = pp[32], p9 = pp[36], pa = pp[40], pb = pp[44];
        float pc = pp[48], pd = pp[52], pe = pp[56], pf = pp[60];
        acc.x += p0*w0.x + p1*w1.x + p2*w2.x + p3*w3.x + p4*w4.x + p5*w5.x + p6*w6.x + p7*w7.x
               + p8*w8.x + p9*w9.x + pa*wa.x + pb*wb.x + pc*wc.x + pd*wd.x + pe*we.x + pf*wf.x;
        acc.y += p0*w0.y + p1*w1.y + p2*w2.y + p3*w3.y + p4*w4.y + p5*w5.y + p6*w6.y + p7*w7.y
               + p8*w8.y + p9*w9.y + pa*wa.y + pb*wb.y + pc*wc.y + pd*wd.y + pe*we.y + pf*wf.y;
        acc.z += p0*w0.z + p1*w1.z + p2*w2.z + p3*w3.z + p4*w4.z + p5*w5.z + p6*w6.z + p7*w7.z
               + p8*w8.z + p9*w9.z + pa*wa.z + pb*wb.z + pc*wc.z + pd*wd.z + pe*we.z + pf*wf.z;
        acc.w += p0*w0.w + p1*w1.w + p2*w2.w + p3*w3.w + p4*w4.w + p5*w5.w + p6*w6.w + p7*w7.w
               + p8*w8.w + p9*w9.w + pa*wa.w + pb*wb.w + pc*wc.w + pd*wd.w + pe*we.w + pf*wf.w;
    }
    acc.x = (acc.x > 0.0f) ? acc.x : expm1f(acc.x);
    acc.y = (acc.y > 0.0f) ? acc.y : expm1f(acc.y);
    acc.z = (acc.z > 0.0f) ? acc.z : expm1f(acc.z);
    acc.w = (acc.w > 0.0f) ? acc.w : expm1f(acc.w);
    ((float4*)hcat[wave])[lane] = acc;

    // phase C: Wh2[row] = hcat[row] @ Wend via LDS-staged Wend tiles (shared by 4 waves)
    __syncthreads();                   // all waves done with u.ps before overwrite
    float a0 = 0.f, a1 = 0.f, a2 = 0.f, a3 = 0.f;
    for (int tile = 0; tile < 8; ++tile) {
        const float4* Wsrc = (const float4*)(Wend + tile * 32 * 64);
        ((float4*)u.wtile)[tid]       = Wsrc[tid];
        ((float4*)u.wtile)[tid + 256] = Wsrc[tid + 256];
        __syncthreads();
        const int jb = tile * 32;
        #pragma unroll
        for (int jj = 0; jj < 32; jj += 4) {
            a0 += hcat[wave][jb + jj    ] * u.wtile[jj    ][lane];
            a1 += hcat[wave][jb + jj + 1] * u.wtile[jj + 1][lane];
            a2 += hcat[wave][jb + jj + 2] * u.wtile[jj + 2][lane];
            a3 += hcat[wave][jb + jj + 3] * u.wtile[jj + 3][lane];
        }
        __syncthreads();
    }
    float aa = (a0 + a1) + (a2 + a3);
    Wh2[(size_t)row * 64 + lane] = aa;
    float s0 = aa * aend[lane], d0 = aa * aend[64 + lane];
    #pragma unroll
    for (int o = 32; o > 0; o >>= 1) {
        s0 += __shfl_xor(s0, o, 64); d0 += __shfl_xor(d0, o, 64);
    }
    if (lane == 0) { src2[row] = s0; dst2[row] = d0; }
}

// ===== K3: layer-2 attention + elu + final row softmax; wave per row; ILP-16 =====
__global__ __launch_bounds__(256) void attn2_kernel(
        const float* __restrict__ Wh2, const float* __restrict__ src,
        const float* __restrict__ dst, const int* __restrict__ cnt,
        const int* __restrict__ idx, float* __restrict__ out) {
    const int wave = threadIdx.x >> 6;
    const int lane = threadIdx.x & 63;
    const int row  = blockIdx.x * 4 + wave;
    const int deg = cnt[row];
    const int* nb = idx + (size_t)row * MAX_DEG;
    const float s_i = src[row];

    float e[4];
    #pragma unroll
    for (int c = 0; c < 4; ++c) {
        int t = c * 64 + lane;
        float ev = -1e30f;
        if (t < deg) {
            int j = nb[t];
            ev = s_i + dst[j];
            ev = (ev > 0.0f) ? ev : ALPHA * ev;
        }
        e[c] = ev;
    }
    float m = fmaxf(fmaxf(e[0], e[1]), fmaxf(e[2], e[3]));
    #pragma unroll
    for (int o = 32; o > 0; o >>= 1) m = fmaxf(m, __shfl_xor(m, o, 64));
    float l = 0.0f;
    #pragma unroll
    for (int c = 0; c < 4; ++c) { e[c] = expf(e[c] - m); l += e[c]; }
    #pragma unroll
    for (int o = 32; o > 0; o >>= 1) l += __shfl_xor(l, o, 64);

    float accA = 0.0f, accB = 0.0f;
    const float* W2 = Wh2 + lane;
    #pragma unroll
    for (int c = 0; c < 4; ++c) {
        int base = c * 64;
        if (base >= deg) break;
        int nmax = deg - base; if (nmax > 64) nmax = 64;
        int n16 = (nmax + 15) & ~15;
        for (int t = 0; t < n16; t += 16) {
            int4 ja = *(const int4*)(nb + base + t);
            int4 jb = *(const int4*)(nb + base + t + 4);
            int4 jc = *(const int4*)(nb + base + t + 8);
            int4 jd = *(const int4*)(nb + base + t + 12);
            float w0 = W2[(size_t)ja.x * 64], w1 = W2[(size_t)ja.y * 64];
            float w2 = W2[(size_t)ja.z * 64], w3 = W2[(size_t)ja.w * 64];
            float w4 = W2[(size_t)jb.x * 64], w5 = W2[(size_t)jb.y * 64];
            float w6 = W2[(size_t)jb.z * 64], w7 = W2[(size_t)jb.w * 64];
            float w8 = W2[(size_t)jc.x * 64], w9 = W2[(size_t)jc.y * 64];
            float wa = W2[(size_t)jc.z * 64], wb = W2[(size_t)jc.w * 64];
            float wc = W2[(size_t)jd.x * 64], wd = W2[(size_t)jd.y * 64];
            float we = W2[(size_t)jd.z * 64], wf = W2[(size_t)jd.w * 64];
            float p0 = __shfl(e[c], t, 64),      p1 = __shfl(e[c], t + 1, 64);
            float p2 = __shfl(e[c], t + 2, 64),  p3 = __shfl(e[c], t + 3, 64);
            float p4 = __shfl(e[c], t + 4, 64),  p5 = __shfl(e[c], t + 5, 64);
            float p6 = __shfl(e[c], t + 6, 64),  p7 = __shfl(e[c], t + 7, 64);
            float p8 = __shfl(e[c], t + 8, 64),  p9 = __shfl(e[c], t + 9, 64);
            float pa = __shfl(e[c], t + 10, 64), pb = __shfl(e[c], t + 11, 64);
            float pc = __shfl(e[c], t + 12, 64), pd = __shfl(e[c], t + 13, 64);
            float pe = __shfl(e[c], t + 14, 64), pf = __shfl(e[c], t + 15, 64);
            accA += p0*w0 + p2*w2 + p4*w4 + p6*w6 + p8*w8 + pa*wa + pc*wc + pe*we;
            accB += p1*w1 + p3*w3 + p5*w5 + p7*w7 + p9*w9 + pb*wb + pd*wd + pf*wf;
        }
    }
    float v = (accA + accB) / l;
    v = (v > 0.0f) ? v : expm1f(v);    // elu

    float mm = v;
    #pragma unroll
    for (int o = 32; o > 0; o >>= 1) mm = fmaxf(mm, __shfl_xor(mm, o, 64));
    float ee = expf(v - mm);
    float ss = ee;
    #pragma unroll
    for (int o = 32; o > 0; o >>= 1) ss += __shfl_xor(ss, o, 64);
    out[(size_t)row * F_OUT + lane] = ee / ss;
}

extern "C" void kernel_launch(void* const* d_in, const int* in_sizes, int n_in,
                              void* d_out, int out_size, void* d_ws, size_t ws_size,
                              hipStream_t stream) {
    const float* x      = (const float*)d_in[0];
    const float* adj    = (const float*)d_in[1];
    const float* lin_W  = (const float*)d_in[2];
    const float* lin_b  = (const float*)d_in[3];
    const float* Wheads = (const float*)d_in[4];
    const float* aheads = (const float*)d_in[5];
    const float* Wend   = (const float*)d_in[6];
    const float* aend   = (const float*)d_in[7];
    float* out = (float*)d_out;

    char* ws = (char*)d_ws;
    float* Wh   = (float*)(ws + OFF_WH);
    float* src1 = (float*)(ws + OFF_SRC1);
    float* dst1 = (float*)(ws + OFF_DST1);
    float* Wh2  = (float*)(ws + OFF_WH2);
    float* src2 = (float*)(ws + OFF_SRC2);
    float* dst2 = (float*)(ws + OFF_DST2);
    int*   cnt  = (int*)(ws + OFF_CNT);
    int*   nidx = (int*)(ws + OFF_IDX);

    prep_kernel<<<NGEMM + GN, 256, 0, stream>>>(adj, x, lin_W, lin_b, Wheads, aheads,
                                                Wh, src1, dst1, cnt, nidx);
    attn_mid_kernel<<<GN / 4, 256, 0, stream>>>(Wh, src1, dst1, Wend, aend,
                                                Wh2, src2, dst2, cnt, nidx);
    attn2_kernel<<<GN / 4, 256, 0, stream>>>(Wh2, src2, dst2, cnt, nidx, out);
}